// Round 1
// baseline (162.228 us; speedup 1.0000x reference)
//
#include <hip/hip_runtime.h>

typedef __attribute__((ext_vector_type(8))) short short8;
typedef __attribute__((ext_vector_type(4))) float f32x4;

#define D 128
#define MARGIN 0.1f

__device__ __forceinline__ unsigned short f32_to_bf16(float f) {
  unsigned int u = __float_as_uint(f);
  u += 0x7fffu + ((u >> 16) & 1u);  // round-to-nearest-even
  return (unsigned short)(u >> 16);
}

__global__ void k_convert(const float* __restrict__ x, unsigned short* __restrict__ xb, int total) {
  int i = (blockIdx.x * blockDim.x + threadIdx.x) * 4;
  if (i + 3 < total) {
    float4 v = *reinterpret_cast<const float4*>(x + i);
    ushort4 o;
    o.x = f32_to_bf16(v.x);
    o.y = f32_to_bf16(v.y);
    o.z = f32_to_bf16(v.z);
    o.w = f32_to_bf16(v.w);
    *reinterpret_cast<ushort4*>(xb + i) = o;
  }
}

// Pass 1: per-row max over negatives / positives.
// Block = 32-row strip x one column-half. 4 waves, 16x16x32 bf16 MFMA, K=128 in regs.
__launch_bounds__(256, 2)
__global__ void k_pass1(const unsigned short* __restrict__ xb, const int* __restrict__ tg,
                        float* __restrict__ mn_part, float* __restrict__ mp_part, int n) {
  const int lane = threadIdx.x & 63;
  const int wid  = threadIdx.x >> 6;
  const int strip = blockIdx.x >> 1;
  const int half  = blockIdx.x & 1;
  const int r0 = strip * 32;
  const int cg   = lane & 15;   // col-in-tile (also A-row-in-tile)
  const int agrp = lane >> 4;   // k-group

  short8 a[2][4];
#pragma unroll
  for (int rt = 0; rt < 2; ++rt)
#pragma unroll
    for (int kk = 0; kk < 4; ++kk)
      a[rt][kk] = *reinterpret_cast<const short8*>(
          xb + (size_t)(r0 + rt * 16 + cg) * D + kk * 32 + agrp * 8);

  int trow[2][4], rowg[2][4];
#pragma unroll
  for (int rt = 0; rt < 2; ++rt)
#pragma unroll
    for (int reg = 0; reg < 4; ++reg) {
      rowg[rt][reg] = r0 + rt * 16 + agrp * 4 + reg;
      trow[rt][reg] = tg[rowg[rt][reg]];
    }

  float mn[2][4], mp[2][4];
#pragma unroll
  for (int rt = 0; rt < 2; ++rt)
#pragma unroll
    for (int reg = 0; reg < 4; ++reg) { mn[rt][reg] = -INFINITY; mp[rt][reg] = -INFINITY; }

  const int nct = n / 32;  // col-tiles per half
  for (int i = wid; i < nct; i += 4) {
    const int ct = half * nct + i;
    const int col = ct * 16 + cg;
    const int tcol = tg[col];
    short8 b[4];
#pragma unroll
    for (int kk = 0; kk < 4; ++kk)
      b[kk] = *reinterpret_cast<const short8*>(xb + (size_t)col * D + kk * 32 + agrp * 8);
#pragma unroll
    for (int rt = 0; rt < 2; ++rt) {
      f32x4 acc = {0.f, 0.f, 0.f, 0.f};
#pragma unroll
      for (int kk = 0; kk < 4; ++kk)
        acc = __builtin_amdgcn_mfma_f32_16x16x32_bf16(a[rt][kk], b[kk], acc, 0, 0, 0);
#pragma unroll
      for (int reg = 0; reg < 4; ++reg) {
        float s = acc[reg];
        bool same = (tcol == trow[rt][reg]);
        float sneg = same ? -INFINITY : s;
        float spos = (same && (col != rowg[rt][reg])) ? s : -INFINITY;
        mn[rt][reg] = fmaxf(mn[rt][reg], sneg);
        mp[rt][reg] = fmaxf(mp[rt][reg], spos);
      }
    }
  }

  // reduce across the 16 lanes of each k-group
#pragma unroll
  for (int m = 1; m < 16; m <<= 1)
#pragma unroll
    for (int rt = 0; rt < 2; ++rt)
#pragma unroll
      for (int reg = 0; reg < 4; ++reg) {
        mn[rt][reg] = fmaxf(mn[rt][reg], __shfl_xor(mn[rt][reg], m, 16));
        mp[rt][reg] = fmaxf(mp[rt][reg], __shfl_xor(mp[rt][reg], m, 16));
      }

  __shared__ float lmn[4][32], lmp[4][32];
  if (cg == 0) {
#pragma unroll
    for (int rt = 0; rt < 2; ++rt)
#pragma unroll
      for (int reg = 0; reg < 4; ++reg) {
        lmn[wid][rt * 16 + agrp * 4 + reg] = mn[rt][reg];
        lmp[wid][rt * 16 + agrp * 4 + reg] = mp[rt][reg];
      }
  }
  __syncthreads();
  if (threadIdx.x < 32) {
    int r = threadIdx.x;
    float vmn = fmaxf(fmaxf(lmn[0][r], lmn[1][r]), fmaxf(lmn[2][r], lmn[3][r]));
    float vmp = fmaxf(fmaxf(lmp[0][r], lmp[1][r]), fmaxf(lmp[2][r], lmp[3][r]));
    mn_part[(size_t)half * n + r0 + r] = vmn;
    mp_part[(size_t)half * n + r0 + r] = vmp;
  }
}

// Pass 2: threshold-selected sums using the pass-1 maxes.
__launch_bounds__(256, 2)
__global__ void k_pass2(const unsigned short* __restrict__ xb, const int* __restrict__ tg,
                        const float* __restrict__ mn_part, const float* __restrict__ mp_part,
                        float* __restrict__ loss_part, int n) {
  const int lane = threadIdx.x & 63;
  const int wid  = threadIdx.x >> 6;
  const int strip = blockIdx.x >> 1;
  const int half  = blockIdx.x & 1;
  const int r0 = strip * 32;
  const int cg   = lane & 15;
  const int agrp = lane >> 4;

  short8 a[2][4];
#pragma unroll
  for (int rt = 0; rt < 2; ++rt)
#pragma unroll
    for (int kk = 0; kk < 4; ++kk)
      a[rt][kk] = *reinterpret_cast<const short8*>(
          xb + (size_t)(r0 + rt * 16 + cg) * D + kk * 32 + agrp * 8);

  int trow[2][4], rowg[2][4];
  float thp[2][4], thn[2][4], hp[2][4];
#pragma unroll
  for (int rt = 0; rt < 2; ++rt)
#pragma unroll
    for (int reg = 0; reg < 4; ++reg) {
      int row = r0 + rt * 16 + agrp * 4 + reg;
      rowg[rt][reg] = row;
      trow[rt][reg] = tg[row];
      float mneg = fmaxf(mn_part[row], mn_part[n + row]);
      float mpos = fmaxf(mp_part[row], mp_part[n + row]);
      thp[rt][reg] = mneg + MARGIN;                 // positives: sim < max_neg + margin
      thn[rt][reg] = fmaxf(0.6f, mpos) - MARGIN;    // negatives: sim > max(0.6,max_pos) - margin
      hp[rt][reg] = (mpos > -1e30f) ? 1.0f : 0.0f;  // has_pos
    }

  float ls[2][4];
#pragma unroll
  for (int rt = 0; rt < 2; ++rt)
#pragma unroll
    for (int reg = 0; reg < 4; ++reg) ls[rt][reg] = 0.f;

  const int nct = n / 32;
  for (int i = wid; i < nct; i += 4) {
    const int ct = half * nct + i;
    const int col = ct * 16 + cg;
    const int tcol = tg[col];
    short8 b[4];
#pragma unroll
    for (int kk = 0; kk < 4; ++kk)
      b[kk] = *reinterpret_cast<const short8*>(xb + (size_t)col * D + kk * 32 + agrp * 8);
#pragma unroll
    for (int rt = 0; rt < 2; ++rt) {
      f32x4 acc = {0.f, 0.f, 0.f, 0.f};
#pragma unroll
      for (int kk = 0; kk < 4; ++kk)
        acc = __builtin_amdgcn_mfma_f32_16x16x32_bf16(a[rt][kk], b[kk], acc, 0, 0, 0);
#pragma unroll
      for (int reg = 0; reg < 4; ++reg) {
        float s = acc[reg];
        bool same = (tcol == trow[rt][reg]);
        bool inpos = same && (col != rowg[rt][reg]) && (s < thp[rt][reg]);
        bool inneg = (!same) && (s > thn[rt][reg]);
        float add = (inpos ? (1.0f - s) : 0.0f) + (inneg ? s : 0.0f);
        ls[rt][reg] += add;
      }
    }
  }

  float tot = 0.f;
#pragma unroll
  for (int rt = 0; rt < 2; ++rt)
#pragma unroll
    for (int reg = 0; reg < 4; ++reg) tot += ls[rt][reg] * hp[rt][reg];

#pragma unroll
  for (int m = 1; m < 64; m <<= 1) tot += __shfl_xor(tot, m, 64);

  __shared__ float lsum[4];
  if (lane == 0) lsum[wid] = tot;
  __syncthreads();
  if (threadIdx.x == 0)
    loss_part[blockIdx.x] = lsum[0] + lsum[1] + lsum[2] + lsum[3];
}

// Diagnostics on the last row, pure f32.
__global__ void k_diag(const float* __restrict__ x, const int* __restrict__ tg,
                       float* __restrict__ dpart, int n) {
  int col = blockIdx.x * blockDim.x + threadIdx.x;
  int R = n - 1;
  int tR = tg[R];
  const float4* xr = reinterpret_cast<const float4*>(x + (size_t)R * D);
  const float4* xc = reinterpret_cast<const float4*>(x + (size_t)col * D);
  float dot = 0.f;
#pragma unroll
  for (int k = 0; k < D / 4; ++k) {
    float4 va = xr[k], vb = xc[k];
    dot += va.x * vb.x + va.y * vb.y + va.z * vb.z + va.w * vb.w;
  }
  int t = tg[col];
  bool same = (t == tR);
  bool isR = (col == R);
  float v[4];
  v[0] = (same && !isR) ? dot : 0.f;
  v[1] = (same && !isR) ? 1.f : 0.f;
  v[2] = (!same) ? dot : 0.f;
  v[3] = (!same) ? 1.f : 0.f;
  int lane = threadIdx.x & 63, wid = threadIdx.x >> 6;
#pragma unroll
  for (int m = 1; m < 64; m <<= 1)
#pragma unroll
    for (int j = 0; j < 4; ++j) v[j] += __shfl_xor(v[j], m, 64);
  __shared__ float red[4][4];
  if (lane == 0) {
#pragma unroll
    for (int j = 0; j < 4; ++j) red[wid][j] = v[j];
  }
  __syncthreads();
  if (threadIdx.x == 0) {
#pragma unroll
    for (int j = 0; j < 4; ++j)
      dpart[blockIdx.x * 4 + j] = red[0][j] + red[1][j] + red[2][j] + red[3][j];
  }
}

__global__ void k_final(const float* __restrict__ loss_part, int nparts,
                        const float* __restrict__ dpart, int ndiag,
                        float* __restrict__ out, int n) {
  float s = 0.f;
  for (int i = threadIdx.x; i < nparts; i += blockDim.x) s += loss_part[i];
  int lane = threadIdx.x & 63, wid = threadIdx.x >> 6;
#pragma unroll
  for (int m = 1; m < 64; m <<= 1) s += __shfl_xor(s, m, 64);
  __shared__ float red[4];
  if (lane == 0) red[wid] = s;
  __syncthreads();
  if (threadIdx.x == 0) {
    float loss = red[0] + red[1] + red[2] + red[3];
    float ps = 0.f, pc = 0.f, ns = 0.f, nc = 0.f;
    for (int b = 0; b < ndiag; ++b) {
      ps += dpart[b * 4 + 0];
      pc += dpart[b * 4 + 1];
      ns += dpart[b * 4 + 2];
      nc += dpart[b * 4 + 3];
    }
    out[0] = loss / (float)n;
    out[1] = 0.f;
    out[2] = 0.f;
    out[3] = 0.f;
    out[4] = ps / fmaxf(pc, 1.f);
    out[5] = ns / fmaxf(nc, 1.f);
  }
}

extern "C" void kernel_launch(void* const* d_in, const int* in_sizes, int n_in,
                              void* d_out, int out_size, void* d_ws, size_t ws_size,
                              hipStream_t stream) {
  const float* x = (const float*)d_in[0];
  const int* tg = (const int*)d_in[1];
  float* out = (float*)d_out;
  int n = in_sizes[1];  // 8192 ; d == 128 assumed (in_sizes[0]/n)

  char* ws = (char*)d_ws;
  unsigned short* xb = (unsigned short*)ws;                    // n*D bf16 = 2 MB
  float* mn_part = (float*)(ws + (size_t)n * D * 2);           // 2*n f32
  float* mp_part = mn_part + 2 * (size_t)n;                    // 2*n f32
  float* loss_part = mp_part + 2 * (size_t)n;                  // nblocks f32
  int nblocks = (n / 32) * 2;
  float* dpart = loss_part + nblocks;                          // (n/256)*4 f32

  int total = n * D;
  k_convert<<<total / 4 / 256, 256, 0, stream>>>(x, xb, total);
  k_pass1<<<nblocks, 256, 0, stream>>>(xb, tg, mn_part, mp_part, n);
  k_pass2<<<nblocks, 256, 0, stream>>>(xb, tg, mn_part, mp_part, loss_part, n);
  int ndiag = n / 256;
  k_diag<<<ndiag, 256, 0, stream>>>(x, tg, dpart, n);
  k_final<<<1, 256, 0, stream>>>(loss_part, nblocks, dpart, ndiag, out, n);
}

// Round 2
// 112.719 us; speedup vs baseline: 1.4392x; 1.4392x over previous
//
#include <hip/hip_runtime.h>

typedef __attribute__((ext_vector_type(8))) short short8;
typedef __attribute__((ext_vector_type(4))) float f32x4;

#define D 128
#define MARGIN 0.1f
#define BM 64   // rows per block
#define NCG 8   // column groups (grid dim 2)

__device__ __forceinline__ unsigned short f32_to_bf16(float f) {
  unsigned int u = __float_as_uint(f);
  u += 0x7fffu + ((u >> 16) & 1u);
  return (unsigned short)(u >> 16);
}

__global__ void k_convert(const float* __restrict__ x, unsigned short* __restrict__ xb, int total) {
  int i = (blockIdx.x * blockDim.x + threadIdx.x) * 4;
  if (i + 3 < total) {
    float4 v = *reinterpret_cast<const float4*>(x + i);
    ushort4 o;
    o.x = f32_to_bf16(v.x);
    o.y = f32_to_bf16(v.y);
    o.z = f32_to_bf16(v.z);
    o.w = f32_to_bf16(v.w);
    *reinterpret_cast<ushort4*>(xb + i) = o;
  }
}

// Pass 1: per-row max over negatives / positives.
// Block = 64-row strip x one column-eighth. 4 waves, 16x16x32 bf16 MFMA,
// K=128 in regs, B double-buffered (1-deep register prefetch).
__launch_bounds__(256)
__global__ void k_pass1(const unsigned short* __restrict__ xb, const int* __restrict__ tg,
                        float* __restrict__ mn_part, float* __restrict__ mp_part, int n) {
  const int lane = threadIdx.x & 63;
  const int wid  = threadIdx.x >> 6;
  const int nstrips = n / BM;
  const int strip = blockIdx.x % nstrips;
  const int cgrp  = blockIdx.x / nstrips;
  const int r0 = strip * BM;
  const int NC = n / NCG;
  const int c0 = cgrp * NC;
  const int cg   = lane & 15;   // col-in-tile (also A-row-in-tile)
  const int agrp = lane >> 4;   // k-group

  short8 a[4][4];
#pragma unroll
  for (int rt = 0; rt < 4; ++rt)
#pragma unroll
    for (int kk = 0; kk < 4; ++kk)
      a[rt][kk] = *reinterpret_cast<const short8*>(
          xb + (size_t)(r0 + rt * 16 + cg) * D + kk * 32 + agrp * 8);

  int trow[4][4], rowg[4][4];
  float mn[4][4], mp[4][4];
#pragma unroll
  for (int rt = 0; rt < 4; ++rt)
#pragma unroll
    for (int reg = 0; reg < 4; ++reg) {
      rowg[rt][reg] = r0 + rt * 16 + agrp * 4 + reg;
      trow[rt][reg] = tg[rowg[rt][reg]];
      mn[rt][reg] = -INFINITY;
      mp[rt][reg] = -INFINITY;
    }

  const int ITERS = NC / 16 / 4;
  const bool hasdiag = (r0 / NC) == cgrp;

  int col = c0 + wid * 16 + cg;
  short8 bc[4];
  int tcc;
#pragma unroll
  for (int kk = 0; kk < 4; ++kk)
    bc[kk] = *reinterpret_cast<const short8*>(xb + (size_t)col * D + kk * 32 + agrp * 8);
  tcc = tg[col];

  if (!hasdiag) {
    for (int i = 0; i < ITERS; ++i) {
      int ncol = (i + 1 < ITERS) ? col + 64 : col;
      short8 bn[4];
#pragma unroll
      for (int kk = 0; kk < 4; ++kk)
        bn[kk] = *reinterpret_cast<const short8*>(xb + (size_t)ncol * D + kk * 32 + agrp * 8);
      int tcn = tg[ncol];
#pragma unroll
      for (int rt = 0; rt < 4; ++rt) {
        f32x4 acc = {0.f, 0.f, 0.f, 0.f};
#pragma unroll
        for (int kk = 0; kk < 4; ++kk)
          acc = __builtin_amdgcn_mfma_f32_16x16x32_bf16(a[rt][kk], bc[kk], acc, 0, 0, 0);
#pragma unroll
        for (int reg = 0; reg < 4; ++reg) {
          float s = acc[reg];
          bool same = (tcc == trow[rt][reg]);
          mn[rt][reg] = fmaxf(mn[rt][reg], same ? -INFINITY : s);
          mp[rt][reg] = fmaxf(mp[rt][reg], same ? s : -INFINITY);
        }
      }
#pragma unroll
      for (int kk = 0; kk < 4; ++kk) bc[kk] = bn[kk];
      tcc = tcn;
      col = ncol;
    }
  } else {
    for (int i = 0; i < ITERS; ++i) {
      int ncol = (i + 1 < ITERS) ? col + 64 : col;
      short8 bn[4];
#pragma unroll
      for (int kk = 0; kk < 4; ++kk)
        bn[kk] = *reinterpret_cast<const short8*>(xb + (size_t)ncol * D + kk * 32 + agrp * 8);
      int tcn = tg[ncol];
#pragma unroll
      for (int rt = 0; rt < 4; ++rt) {
        f32x4 acc = {0.f, 0.f, 0.f, 0.f};
#pragma unroll
        for (int kk = 0; kk < 4; ++kk)
          acc = __builtin_amdgcn_mfma_f32_16x16x32_bf16(a[rt][kk], bc[kk], acc, 0, 0, 0);
#pragma unroll
        for (int reg = 0; reg < 4; ++reg) {
          float s = acc[reg];
          bool same = (tcc == trow[rt][reg]);
          mn[rt][reg] = fmaxf(mn[rt][reg], same ? -INFINITY : s);
          mp[rt][reg] = fmaxf(mp[rt][reg],
                              (same && (col != rowg[rt][reg])) ? s : -INFINITY);
        }
      }
#pragma unroll
      for (int kk = 0; kk < 4; ++kk) bc[kk] = bn[kk];
      tcc = tcn;
      col = ncol;
    }
  }

  // reduce across the 16 cg-lanes of each k-group
#pragma unroll
  for (int m = 1; m < 16; m <<= 1)
#pragma unroll
    for (int rt = 0; rt < 4; ++rt)
#pragma unroll
      for (int reg = 0; reg < 4; ++reg) {
        mn[rt][reg] = fmaxf(mn[rt][reg], __shfl_xor(mn[rt][reg], m, 16));
        mp[rt][reg] = fmaxf(mp[rt][reg], __shfl_xor(mp[rt][reg], m, 16));
      }

  __shared__ float lmn[4][BM], lmp[4][BM];
  if (cg == 0) {
#pragma unroll
    for (int rt = 0; rt < 4; ++rt)
#pragma unroll
      for (int reg = 0; reg < 4; ++reg) {
        lmn[wid][rt * 16 + agrp * 4 + reg] = mn[rt][reg];
        lmp[wid][rt * 16 + agrp * 4 + reg] = mp[rt][reg];
      }
  }
  __syncthreads();
  if (threadIdx.x < BM) {
    int r = threadIdx.x;
    float vmn = fmaxf(fmaxf(lmn[0][r], lmn[1][r]), fmaxf(lmn[2][r], lmn[3][r]));
    float vmp = fmaxf(fmaxf(lmp[0][r], lmp[1][r]), fmaxf(lmp[2][r], lmp[3][r]));
    mn_part[(size_t)cgrp * n + r0 + r] = vmn;
    mp_part[(size_t)cgrp * n + r0 + r] = vmp;
  }
}

// Pass 2: threshold-selected sums using the pass-1 maxes.
__launch_bounds__(256)
__global__ void k_pass2(const unsigned short* __restrict__ xb, const int* __restrict__ tg,
                        const float* __restrict__ mn_part, const float* __restrict__ mp_part,
                        float* __restrict__ loss_part, int n) {
  const int lane = threadIdx.x & 63;
  const int wid  = threadIdx.x >> 6;
  const int nstrips = n / BM;
  const int strip = blockIdx.x % nstrips;
  const int cgrp  = blockIdx.x / nstrips;
  const int r0 = strip * BM;
  const int NC = n / NCG;
  const int c0 = cgrp * NC;
  const int cg   = lane & 15;
  const int agrp = lane >> 4;

  short8 a[4][4];
#pragma unroll
  for (int rt = 0; rt < 4; ++rt)
#pragma unroll
    for (int kk = 0; kk < 4; ++kk)
      a[rt][kk] = *reinterpret_cast<const short8*>(
          xb + (size_t)(r0 + rt * 16 + cg) * D + kk * 32 + agrp * 8);

  int trow[4][4], rowg[4][4];
  float thp[4][4], thn[4][4], ls[4][4];
#pragma unroll
  for (int rt = 0; rt < 4; ++rt)
#pragma unroll
    for (int reg = 0; reg < 4; ++reg) {
      int row = r0 + rt * 16 + agrp * 4 + reg;
      rowg[rt][reg] = row;
      trow[rt][reg] = tg[row];
      float mneg = -INFINITY, mpos = -INFINITY;
#pragma unroll
      for (int g = 0; g < NCG; ++g) {
        mneg = fmaxf(mneg, mn_part[(size_t)g * n + row]);
        mpos = fmaxf(mpos, mp_part[(size_t)g * n + row]);
      }
      thp[rt][reg] = mneg + MARGIN;
      // fold has_pos into thresholds: no positives -> select nothing at all
      thn[rt][reg] = (mpos > -1e30f) ? (fmaxf(0.6f, mpos) - MARGIN) : INFINITY;
      ls[rt][reg] = 0.f;
    }

  const int ITERS = NC / 16 / 4;
  const bool hasdiag = (r0 / NC) == cgrp;

  int col = c0 + wid * 16 + cg;
  short8 bc[4];
  int tcc;
#pragma unroll
  for (int kk = 0; kk < 4; ++kk)
    bc[kk] = *reinterpret_cast<const short8*>(xb + (size_t)col * D + kk * 32 + agrp * 8);
  tcc = tg[col];

  if (!hasdiag) {
    for (int i = 0; i < ITERS; ++i) {
      int ncol = (i + 1 < ITERS) ? col + 64 : col;
      short8 bn[4];
#pragma unroll
      for (int kk = 0; kk < 4; ++kk)
        bn[kk] = *reinterpret_cast<const short8*>(xb + (size_t)ncol * D + kk * 32 + agrp * 8);
      int tcn = tg[ncol];
#pragma unroll
      for (int rt = 0; rt < 4; ++rt) {
        f32x4 acc = {0.f, 0.f, 0.f, 0.f};
#pragma unroll
        for (int kk = 0; kk < 4; ++kk)
          acc = __builtin_amdgcn_mfma_f32_16x16x32_bf16(a[rt][kk], bc[kk], acc, 0, 0, 0);
#pragma unroll
        for (int reg = 0; reg < 4; ++reg) {
          float s = acc[reg];
          bool same = (tcc == trow[rt][reg]);
          bool inpos = same && (s < thp[rt][reg]);
          bool inneg = (!same) && (s > thn[rt][reg]);
          ls[rt][reg] += inpos ? (1.0f - s) : (inneg ? s : 0.0f);
        }
      }
#pragma unroll
      for (int kk = 0; kk < 4; ++kk) bc[kk] = bn[kk];
      tcc = tcn;
      col = ncol;
    }
  } else {
    for (int i = 0; i < ITERS; ++i) {
      int ncol = (i + 1 < ITERS) ? col + 64 : col;
      short8 bn[4];
#pragma unroll
      for (int kk = 0; kk < 4; ++kk)
        bn[kk] = *reinterpret_cast<const short8*>(xb + (size_t)ncol * D + kk * 32 + agrp * 8);
      int tcn = tg[ncol];
#pragma unroll
      for (int rt = 0; rt < 4; ++rt) {
        f32x4 acc = {0.f, 0.f, 0.f, 0.f};
#pragma unroll
        for (int kk = 0; kk < 4; ++kk)
          acc = __builtin_amdgcn_mfma_f32_16x16x32_bf16(a[rt][kk], bc[kk], acc, 0, 0, 0);
#pragma unroll
        for (int reg = 0; reg < 4; ++reg) {
          float s = acc[reg];
          bool same = (tcc == trow[rt][reg]);
          bool notdiag = (col != rowg[rt][reg]);
          bool inpos = same && notdiag && (s < thp[rt][reg]);
          bool inneg = (!same) && (s > thn[rt][reg]);
          ls[rt][reg] += inpos ? (1.0f - s) : (inneg ? s : 0.0f);
        }
      }
#pragma unroll
      for (int kk = 0; kk < 4; ++kk) bc[kk] = bn[kk];
      tcc = tcn;
      col = ncol;
    }
  }

  float tot = 0.f;
#pragma unroll
  for (int rt = 0; rt < 4; ++rt)
#pragma unroll
    for (int reg = 0; reg < 4; ++reg) tot += ls[rt][reg];

#pragma unroll
  for (int m = 1; m < 64; m <<= 1) tot += __shfl_xor(tot, m, 64);

  __shared__ float lsum[4];
  if (lane == 0) lsum[wid] = tot;
  __syncthreads();
  if (threadIdx.x == 0)
    loss_part[blockIdx.x] = lsum[0] + lsum[1] + lsum[2] + lsum[3];
}

// Diagnostics on the last row, pure f32.
__global__ void k_diag(const float* __restrict__ x, const int* __restrict__ tg,
                       float* __restrict__ dpart, int n) {
  int col = blockIdx.x * blockDim.x + threadIdx.x;
  int R = n - 1;
  int tR = tg[R];
  const float4* xr = reinterpret_cast<const float4*>(x + (size_t)R * D);
  const float4* xc = reinterpret_cast<const float4*>(x + (size_t)col * D);
  float dot = 0.f;
#pragma unroll
  for (int k = 0; k < D / 4; ++k) {
    float4 va = xr[k], vb = xc[k];
    dot += va.x * vb.x + va.y * vb.y + va.z * vb.z + va.w * vb.w;
  }
  int t = tg[col];
  bool same = (t == tR);
  bool isR = (col == R);
  float v[4];
  v[0] = (same && !isR) ? dot : 0.f;
  v[1] = (same && !isR) ? 1.f : 0.f;
  v[2] = (!same) ? dot : 0.f;
  v[3] = (!same) ? 1.f : 0.f;
  int lane = threadIdx.x & 63, wid = threadIdx.x >> 6;
#pragma unroll
  for (int m = 1; m < 64; m <<= 1)
#pragma unroll
    for (int j = 0; j < 4; ++j) v[j] += __shfl_xor(v[j], m, 64);
  __shared__ float red[4][4];
  if (lane == 0) {
#pragma unroll
    for (int j = 0; j < 4; ++j) red[wid][j] = v[j];
  }
  __syncthreads();
  if (threadIdx.x == 0) {
#pragma unroll
    for (int j = 0; j < 4; ++j)
      dpart[blockIdx.x * 4 + j] = red[0][j] + red[1][j] + red[2][j] + red[3][j];
  }
}

__global__ void k_final(const float* __restrict__ loss_part, int nparts,
                        const float* __restrict__ dpart, int ndiag,
                        float* __restrict__ out, int n) {
  float s = 0.f;
  for (int i = threadIdx.x; i < nparts; i += blockDim.x) s += loss_part[i];
  int lane = threadIdx.x & 63, wid = threadIdx.x >> 6;
#pragma unroll
  for (int m = 1; m < 64; m <<= 1) s += __shfl_xor(s, m, 64);
  __shared__ float red[4];
  if (lane == 0) red[wid] = s;
  __syncthreads();
  if (threadIdx.x == 0) {
    float loss = red[0] + red[1] + red[2] + red[3];
    float ps = 0.f, pc = 0.f, ns = 0.f, nc = 0.f;
    for (int b = 0; b < ndiag; ++b) {
      ps += dpart[b * 4 + 0];
      pc += dpart[b * 4 + 1];
      ns += dpart[b * 4 + 2];
      nc += dpart[b * 4 + 3];
    }
    out[0] = loss / (float)n;
    out[1] = 0.f;
    out[2] = 0.f;
    out[3] = 0.f;
    out[4] = ps / fmaxf(pc, 1.f);
    out[5] = ns / fmaxf(nc, 1.f);
  }
}

extern "C" void kernel_launch(void* const* d_in, const int* in_sizes, int n_in,
                              void* d_out, int out_size, void* d_ws, size_t ws_size,
                              hipStream_t stream) {
  const float* x = (const float*)d_in[0];
  const int* tg = (const int*)d_in[1];
  float* out = (float*)d_out;
  int n = in_sizes[1];  // 8192

  char* ws = (char*)d_ws;
  unsigned short* xb = (unsigned short*)ws;                    // n*D bf16 = 2 MB
  float* mn_part = (float*)(ws + (size_t)n * D * 2);           // NCG*n f32
  float* mp_part = mn_part + (size_t)NCG * n;                  // NCG*n f32
  float* loss_part = mp_part + (size_t)NCG * n;                // nblocks f32
  int nblocks = (n / BM) * NCG;
  float* dpart = loss_part + nblocks;                          // (n/256)*4 f32

  int total = n * D;
  k_convert<<<total / 4 / 256, 256, 0, stream>>>(x, xb, total);
  k_pass1<<<nblocks, 256, 0, stream>>>(xb, tg, mn_part, mp_part, n);
  k_pass2<<<nblocks, 256, 0, stream>>>(xb, tg, mn_part, mp_part, loss_part, n);
  int ndiag = n / 256;
  k_diag<<<ndiag, 256, 0, stream>>>(x, tg, dpart, n);
  k_final<<<1, 256, 0, stream>>>(loss_part, nblocks, dpart, ndiag, out, n);
}